// Round 2
// baseline (483.992 us; speedup 1.0000x reference)
//
#include <hip/hip_runtime.h>

#define N_NODES 100000

// ---------- edge-index access (handles int32 or raw int64 little-endian) ----
__device__ __forceinline__ int edge_at(const int* __restrict__ ei, int idx, int is64) {
    return is64 ? ei[2 * idx] : ei[idx];
}

// ---------- init: zero counts + detection flag --------------------------------
__global__ void k_init(int* __restrict__ count, int* __restrict__ flag) {
    int i = blockIdx.x * 256 + threadIdx.x;
    if (i < N_NODES) count[i] = 0;
    if (i == 0) flag[0] = 0;
}

// flag[0] = 1 if buffer is int32 layout (some odd 32-bit word nonzero).
// For int64 values < 2^31 the high words are all zero.
__global__ void k_detect(const int* __restrict__ ei, int* __restrict__ flag) {
    int t = threadIdx.x;
    int any = 0;
    for (int i = t; i < 4096; i += 256) any |= ei[2 * i + 1];
    if (any) atomicOr(flag, 1);
}

// ---------- degree count over dst --------------------------------------------
__global__ void k_count(const int* __restrict__ ei, int* __restrict__ count, int E,
                        const int* __restrict__ flag) {
    int e = blockIdx.x * 256 + threadIdx.x;
    if (e >= E) return;
    int is64 = (flag[0] == 0);
    int d = edge_at(ei, E + e, is64);
    atomicAdd(&count[d], 1);
}

// ---------- 3-kernel exclusive scan of count -> offs --------------------------
__global__ __launch_bounds__(256) void k_scan1(const int* __restrict__ count,
                                               int* __restrict__ offs,
                                               int* __restrict__ bsum) {
    __shared__ int s[256];
    int t = threadIdx.x;
    int i = blockIdx.x * 256 + t;
    int v = (i < N_NODES) ? count[i] : 0;
    s[t] = v;
    __syncthreads();
    for (int d = 1; d < 256; d <<= 1) {
        int y = (t >= d) ? s[t - d] : 0;
        __syncthreads();
        s[t] += y;
        __syncthreads();
    }
    if (i < N_NODES) offs[i] = s[t] - v;          // exclusive within block
    if (t == 255) bsum[blockIdx.x] = s[255];       // block total
}

__global__ void k_scan2(int* __restrict__ bsum, int NB) {
    __shared__ int s[512];
    int t = threadIdx.x;
    s[t] = (t < NB) ? bsum[t] : 0;
    __syncthreads();
    if (t == 0) {
        int run = 0;
        for (int b = 0; b < NB; ++b) { int v = s[b]; s[b] = run; run += v; }
    }
    __syncthreads();
    if (t < NB) bsum[t] = s[t];                    // exclusive block offsets
}

__global__ void k_scan3(int* __restrict__ offs, const int* __restrict__ bsum,
                        int* __restrict__ cursor, const int* __restrict__ count,
                        float* __restrict__ dis) {
    int i = blockIdx.x * 256 + threadIdx.x;
    if (i >= N_NODES) return;
    int o = offs[i] + bsum[blockIdx.x];
    offs[i] = o;
    cursor[i] = o;
    dis[i] = rsqrtf((float)count[i] + 1.0f);       // deg includes self-loop
}

// ---------- CSR fill (srcs grouped by dst) -----------------------------------
__global__ void k_fill(const int* __restrict__ ei, int* __restrict__ cursor,
                       int* __restrict__ srcs, int E, const int* __restrict__ flag) {
    int e = blockIdx.x * 256 + threadIdx.x;
    if (e >= E) return;
    int is64 = (flag[0] == 0);
    int d = edge_at(ei, E + e, is64);
    int s = edge_at(ei, e, is64);
    int p = atomicAdd(&cursor[d], 1);
    srcs[p] = s;
}

// ---------- GEMM1: y1 = (x @ W1) * dis[row]  [100000,128]x[128,128] ----------
// 32-row tile per block; W staged in LDS in two 64-row halves (48KB total LDS).
__global__ __launch_bounds__(256) void k_gemm1(const float* __restrict__ x,
                                               const float* __restrict__ W,
                                               const float* __restrict__ dis,
                                               float* __restrict__ y1) {
    __shared__ float Wl[64 * 128];   // 32 KB
    __shared__ float Xl[32 * 128];   // 16 KB
    int t = threadIdx.x;
    int row0 = blockIdx.x * 32;

    const float4* X4 = (const float4*)(x + (size_t)row0 * 128);
    float4* Xl4 = (float4*)Xl;
#pragma unroll
    for (int i = 0; i < 4; ++i) Xl4[t + 256 * i] = X4[t + 256 * i];

    int cg = t & 31;   // cols 4cg..4cg+3
    int rg = t >> 5;   // rows 4rg..4rg+3
    float acc[4][4] = {};
    float4* Wl4 = (float4*)Wl;
    const float4* W4 = (const float4*)W;

    for (int kh = 0; kh < 2; ++kh) {
        __syncthreads();  // Xl ready (kh=0) / Wl drained (kh=1)
#pragma unroll
        for (int i = 0; i < 8; ++i) Wl4[t + 256 * i] = W4[kh * 2048 + t + 256 * i];
        __syncthreads();
        for (int k = 0; k < 64; ++k) {
            float4 w = Wl4[k * 32 + cg];
#pragma unroll
            for (int r = 0; r < 4; ++r) {
                float xv = Xl[(4 * rg + r) * 128 + kh * 64 + k];
                acc[r][0] = fmaf(xv, w.x, acc[r][0]);
                acc[r][1] = fmaf(xv, w.y, acc[r][1]);
                acc[r][2] = fmaf(xv, w.z, acc[r][2]);
                acc[r][3] = fmaf(xv, w.w, acc[r][3]);
            }
        }
    }
#pragma unroll
    for (int r = 0; r < 4; ++r) {
        int row = row0 + 4 * rg + r;
        float dd = dis[row];
        float4 o;
        o.x = acc[r][0] * dd; o.y = acc[r][1] * dd;
        o.z = acc[r][2] * dd; o.w = acc[r][3] * dd;
        ((float4*)y1)[row * 32 + cg] = o;
    }
}

// ---------- Aggregation 1: h = relu(dis[d]*(y1[d] + sum y1[src]) + b1) -------
// One wave (64 lanes) per node; lane handles 2 consecutive floats (float2).
__global__ __launch_bounds__(256) void k_agg1(const float* __restrict__ y1,
                                              const int* __restrict__ srcs,
                                              const int* __restrict__ offs,
                                              const int* __restrict__ count,
                                              const float* __restrict__ dis,
                                              const float* __restrict__ b1,
                                              float* __restrict__ h) {
    int wave = (blockIdx.x * 256 + threadIdx.x) >> 6;
    int lane = threadIdx.x & 63;
    if (wave >= N_NODES) return;
    int d = wave;
    const float2* yp = (const float2*)y1;
    float2 acc = yp[(size_t)d * 64 + lane];        // self-loop term
    int st = offs[d], n = count[d];
    for (int i = 0; i < n; ++i) {
        int s = srcs[st + i];
        float2 v = yp[(size_t)s * 64 + lane];
        acc.x += v.x; acc.y += v.y;
    }
    float dd = dis[d];
    float2 b = ((const float2*)b1)[lane];
    float hx = fmaxf(fmaf(acc.x, dd, b.x), 0.0f);
    float hy = fmaxf(fmaf(acc.y, dd, b.y), 0.0f);
    ((float2*)h)[(size_t)d * 64 + lane] = make_float2(hx, hy);
}

// ---------- GEMM2: y2 = (h @ W2) * dis[row]  [100000,128]x[128,8] ------------
__global__ __launch_bounds__(256) void k_gemm2(const float* __restrict__ h,
                                               const float* __restrict__ W2,
                                               const float* __restrict__ dis,
                                               float* __restrict__ y2) {
    __shared__ float Hl[32][129];
    __shared__ float W2l[128 * 8];
    int t = threadIdx.x;
    for (int i = t; i < 1024; i += 256) W2l[i] = W2[i];
    int row0 = blockIdx.x * 32;
    const float4* H4 = (const float4*)(h + (size_t)row0 * 128);
#pragma unroll
    for (int i = 0; i < 4; ++i) {
        int idx = t + 256 * i;          // float4 index in 32x128 tile
        float4 v = H4[idx];
        int r = idx >> 5, c = (idx & 31) * 4;
        Hl[r][c] = v.x; Hl[r][c + 1] = v.y; Hl[r][c + 2] = v.z; Hl[r][c + 3] = v.w;
    }
    __syncthreads();
    int r = t >> 3, c = t & 7;
    float acc = 0.0f;
    for (int k = 0; k < 128; ++k) acc = fmaf(Hl[r][k], W2l[k * 8 + c], acc);
    int row = row0 + r;
    y2[(size_t)row * 8 + c] = acc * dis[row];
}

// ---------- Aggregation 2 + bias + log_softmax -> out ------------------------
// 8 lanes per node (one per class).
__global__ __launch_bounds__(256) void k_agg2(const float* __restrict__ y2,
                                              const int* __restrict__ srcs,
                                              const int* __restrict__ offs,
                                              const int* __restrict__ count,
                                              const float* __restrict__ dis,
                                              const float* __restrict__ b2,
                                              float* __restrict__ out) {
    int g = (blockIdx.x * 256 + threadIdx.x) >> 3;   // node
    int c = threadIdx.x & 7;                         // class
    if (g >= N_NODES) return;
    float acc = y2[(size_t)g * 8 + c];               // self-loop term
    int st = offs[g], n = count[g];
    for (int i = 0; i < n; ++i) {
        int s = srcs[st + i];
        acc += y2[(size_t)s * 8 + c];
    }
    float o = fmaf(acc, dis[g], b2[c]);
    float m = o;
#pragma unroll
    for (int k = 1; k < 8; k <<= 1) m = fmaxf(m, __shfl_xor(m, k, 64));
    float e = expf(o - m);
    float ssum = e;
#pragma unroll
    for (int k = 1; k < 8; k <<= 1) ssum += __shfl_xor(ssum, k, 64);
    out[(size_t)g * 8 + c] = (o - m) - logf(ssum);
}

// ---------- host launcher -----------------------------------------------------
extern "C" void kernel_launch(void* const* d_in, const int* in_sizes, int n_in,
                              void* d_out, int out_size, void* d_ws, size_t ws_size,
                              hipStream_t stream) {
    const float* x  = (const float*)d_in[0];
    const int*   ei = (const int*)d_in[1];
    const float* W1 = (const float*)d_in[2];
    const float* b1 = (const float*)d_in[3];
    const float* W2 = (const float*)d_in[4];
    const float* b2 = (const float*)d_in[5];
    float* out = (float*)d_out;
    const int E = in_sizes[1] / 2;     // logical edge count

    // workspace layout (all 16B-aligned)
    char* ws = (char*)d_ws;
    int*   flag   = (int*)ws;                       // 4 B (pad to 256)
    int*   count  = (int*)(ws + 256);               // N ints
    int*   offs   = count + N_NODES;                // N ints
    int*   cursor = offs + N_NODES;                 // N ints
    int*   bsum   = cursor + N_NODES;               // 512 ints
    float* dis    = (float*)(bsum + 512);           // N floats
    int*   srcs   = (int*)(dis + N_NODES);          // E ints
    float* y1     = (float*)(srcs + E);             // N*128 floats
    float* h      = y1 + (size_t)N_NODES * 128;     // N*128 floats
    float* y2     = h + (size_t)N_NODES * 128;      // N*8 floats

    const int NB = (N_NODES + 255) / 256;           // 391
    const int EB = (E + 255) / 256;

    k_init  <<<NB, 256, 0, stream>>>(count, flag);
    k_detect<<<1, 256, 0, stream>>>(ei, flag);
    k_count <<<EB, 256, 0, stream>>>(ei, count, E, flag);
    k_scan1 <<<NB, 256, 0, stream>>>(count, offs, bsum);
    k_scan2 <<<1, 512, 0, stream>>>(bsum, NB);
    k_scan3 <<<NB, 256, 0, stream>>>(offs, bsum, cursor, count, dis);
    k_fill  <<<EB, 256, 0, stream>>>(ei, cursor, srcs, E, flag);

    k_gemm1 <<<N_NODES / 32, 256, 0, stream>>>(x, W1, dis, y1);
    k_agg1  <<<(N_NODES + 3) / 4, 256, 0, stream>>>(y1, srcs, offs, count, dis, b1, h);
    k_gemm2 <<<N_NODES / 32, 256, 0, stream>>>(h, W2, dis, y2);
    k_agg2  <<<(N_NODES + 31) / 32, 256, 0, stream>>>(y2, srcs, offs, count, dis, b2, out);
}

// Round 3
// 397.013 us; speedup vs baseline: 1.2191x; 1.2191x over previous
//
#include <hip/hip_runtime.h>

#define N_NODES 100000

typedef unsigned int uint;

// ---------- bf16 helpers ------------------------------------------------------
__device__ __forceinline__ uint pack_bf16_2(float a, float b) {
    uint ua = __float_as_uint(a), ub = __float_as_uint(b);
    ua += 0x7fff + ((ua >> 16) & 1);           // RNE
    ub += 0x7fff + ((ub >> 16) & 1);
    return (ua >> 16) | (ub & 0xffff0000u);
}
__device__ __forceinline__ float bf_lo(uint u) { return __uint_as_float(u << 16); }
__device__ __forceinline__ float bf_hi(uint u) { return __uint_as_float(u & 0xffff0000u); }

// ---------- edge-index access (handles int32 or raw int64 little-endian) ----
__device__ __forceinline__ int edge_at(const int* __restrict__ ei, int idx, int is64) {
    return is64 ? ei[2 * idx] : ei[idx];
}

// ---------- init: zero counts + int32/int64 layout probe (block 0) -----------
__global__ void k_init(int* __restrict__ count, int* __restrict__ flag,
                       const int* __restrict__ ei) {
    int i = blockIdx.x * 256 + threadIdx.x;
    if (i < N_NODES) count[i] = 0;
    if (blockIdx.x == 0) {
        if (threadIdx.x == 0) flag[0] = 0;
        __syncthreads();
        int any = 0;
        for (int j = threadIdx.x; j < 4096; j += 256) any |= ei[2 * j + 1];
        if (any) atomicOr(flag, 1);            // int32 layout
    }
}

// ---------- degree count over dst --------------------------------------------
__global__ void k_count(const int* __restrict__ ei, int* __restrict__ count, int E,
                        const int* __restrict__ flag) {
    int e = blockIdx.x * 256 + threadIdx.x;
    if (e >= E) return;
    int is64 = (flag[0] == 0);
    int d = edge_at(ei, E + e, is64);
    atomicAdd(&count[d], 1);
}

// ---------- 3-kernel exclusive scan of count -> offs --------------------------
__global__ __launch_bounds__(256) void k_scan1(const int* __restrict__ count,
                                               int* __restrict__ offs,
                                               int* __restrict__ bsum) {
    __shared__ int s[256];
    int t = threadIdx.x;
    int i = blockIdx.x * 256 + t;
    int v = (i < N_NODES) ? count[i] : 0;
    s[t] = v;
    __syncthreads();
    for (int d = 1; d < 256; d <<= 1) {
        int y = (t >= d) ? s[t - d] : 0;
        __syncthreads();
        s[t] += y;
        __syncthreads();
    }
    if (i < N_NODES) offs[i] = s[t] - v;
    if (t == 255) bsum[blockIdx.x] = s[255];
}

__global__ void k_scan2(int* __restrict__ bsum, int NB) {
    __shared__ int s[512];
    int t = threadIdx.x;
    s[t] = (t < NB) ? bsum[t] : 0;
    __syncthreads();
    if (t == 0) {
        int run = 0;
        for (int b = 0; b < NB; ++b) { int v = s[b]; s[b] = run; run += v; }
    }
    __syncthreads();
    if (t < NB) bsum[t] = s[t];
}

__global__ void k_scan3(int* __restrict__ offs, const int* __restrict__ bsum,
                        int* __restrict__ cursor, const int* __restrict__ count,
                        float* __restrict__ dis) {
    int i = blockIdx.x * 256 + threadIdx.x;
    if (i >= N_NODES) return;
    int o = offs[i] + bsum[blockIdx.x];
    offs[i] = o;
    cursor[i] = o;
    dis[i] = rsqrtf((float)count[i] + 1.0f);   // deg includes self-loop
}

// ---------- CSR fill (srcs grouped by dst) -----------------------------------
__global__ void k_fill(const int* __restrict__ ei, int* __restrict__ cursor,
                       int* __restrict__ srcs, int E, const int* __restrict__ flag) {
    int e = blockIdx.x * 256 + threadIdx.x;
    if (e >= E) return;
    int is64 = (flag[0] == 0);
    int d = edge_at(ei, E + e, is64);
    int s = edge_at(ei, e, is64);
    int p = atomicAdd(&cursor[d], 1);
    srcs[p] = s;
}

// ---------- GEMM1: y1 = bf16((x @ W1) * dis[row])  [100000,128]x[128,128] ----
__global__ __launch_bounds__(256) void k_gemm1(const float* __restrict__ x,
                                               const float* __restrict__ W,
                                               const float* __restrict__ dis,
                                               uint* __restrict__ y1) {
    __shared__ float Wl[64 * 128];   // 32 KB
    __shared__ float Xl[32 * 128];   // 16 KB
    int t = threadIdx.x;
    int row0 = blockIdx.x * 32;

    const float4* X4 = (const float4*)(x + (size_t)row0 * 128);
    float4* Xl4 = (float4*)Xl;
#pragma unroll
    for (int i = 0; i < 4; ++i) Xl4[t + 256 * i] = X4[t + 256 * i];

    int cg = t & 31;   // cols 4cg..4cg+3
    int rg = t >> 5;   // rows 4rg..4rg+3
    float acc[4][4] = {};
    float4* Wl4 = (float4*)Wl;
    const float4* W4 = (const float4*)W;

    for (int kh = 0; kh < 2; ++kh) {
        __syncthreads();
#pragma unroll
        for (int i = 0; i < 8; ++i) Wl4[t + 256 * i] = W4[kh * 2048 + t + 256 * i];
        __syncthreads();
        for (int k = 0; k < 64; ++k) {
            float4 w = Wl4[k * 32 + cg];
#pragma unroll
            for (int r = 0; r < 4; ++r) {
                float xv = Xl[(4 * rg + r) * 128 + kh * 64 + k];
                acc[r][0] = fmaf(xv, w.x, acc[r][0]);
                acc[r][1] = fmaf(xv, w.y, acc[r][1]);
                acc[r][2] = fmaf(xv, w.z, acc[r][2]);
                acc[r][3] = fmaf(xv, w.w, acc[r][3]);
            }
        }
    }
#pragma unroll
    for (int r = 0; r < 4; ++r) {
        int row = row0 + 4 * rg + r;
        float dd = dis[row];
        uint2 o;
        o.x = pack_bf16_2(acc[r][0] * dd, acc[r][1] * dd);
        o.y = pack_bf16_2(acc[r][2] * dd, acc[r][3] * dd);
        ((uint2*)y1)[row * 32 + cg] = o;       // row = 64 uints = 32 uint2
    }
}

// ---------- Aggregation 1 fused with GEMM2 -----------------------------------
// One wave per node. h-row (128 vals, 2/lane) never hits memory:
//   h = relu(dis[d]*(y1[d] + sum y1[src]) + b1);  y2[d] = (h @ W2) * dis[d]
__global__ __launch_bounds__(256) void k_agg1(const uint* __restrict__ y1,
                                              const int* __restrict__ srcs,
                                              const int* __restrict__ offs,
                                              const int* __restrict__ count,
                                              const float* __restrict__ dis,
                                              const float* __restrict__ b1,
                                              const float* __restrict__ W2,
                                              float* __restrict__ y2) {
    __shared__ float W2l[128 * 8];             // 4 KB
    int t = threadIdx.x;
    for (int i = t; i < 1024; i += 256) W2l[i] = W2[i];
    __syncthreads();

    int wave = (blockIdx.x * 256 + t) >> 6;
    int lane = t & 63;
    if (wave >= N_NODES) return;
    int d = wave;

    uint us = y1[(size_t)d * 64 + lane];       // self-loop term
    float ax = bf_lo(us), ay = bf_hi(us);
    float bx = 0.0f, by = 0.0f;                // second accumulator pair (ILP)

    int st = offs[d], n = count[d];
    int i = 0;
    for (; i + 4 <= n; i += 4) {               // 4 independent gathers in flight
        int s0 = srcs[st + i], s1 = srcs[st + i + 1];
        int s2 = srcs[st + i + 2], s3 = srcs[st + i + 3];
        uint u0 = y1[(size_t)s0 * 64 + lane];
        uint u1 = y1[(size_t)s1 * 64 + lane];
        uint u2 = y1[(size_t)s2 * 64 + lane];
        uint u3 = y1[(size_t)s3 * 64 + lane];
        ax += bf_lo(u0); ay += bf_hi(u0);
        bx += bf_lo(u1); by += bf_hi(u1);
        ax += bf_lo(u2); ay += bf_hi(u2);
        bx += bf_lo(u3); by += bf_hi(u3);
    }
    for (; i < n; ++i) {
        uint u = y1[(size_t)srcs[st + i] * 64 + lane];
        ax += bf_lo(u); ay += bf_hi(u);
    }
    ax += bx; ay += by;

    float dd = dis[d];
    float2 b = ((const float2*)b1)[lane];
    float h0 = fmaxf(fmaf(ax, dd, b.x), 0.0f);
    float h1 = fmaxf(fmaf(ay, dd, b.y), 0.0f);

    // fused GEMM2: p[c] = h0*W2[2*lane][c] + h1*W2[2*lane+1][c], reduce over lanes
    const float4* wrow = (const float4*)&W2l[2 * lane * 8];
    float4 wa0 = wrow[0], wa1 = wrow[1];       // row 2*lane
    float4 wb0 = wrow[2], wb1 = wrow[3];       // row 2*lane+1
    float p[8];
    p[0] = h0 * wa0.x + h1 * wb0.x;  p[1] = h0 * wa0.y + h1 * wb0.y;
    p[2] = h0 * wa0.z + h1 * wb0.z;  p[3] = h0 * wa0.w + h1 * wb0.w;
    p[4] = h0 * wa1.x + h1 * wb1.x;  p[5] = h0 * wa1.y + h1 * wb1.y;
    p[6] = h0 * wa1.z + h1 * wb1.z;  p[7] = h0 * wa1.w + h1 * wb1.w;
#pragma unroll
    for (int s = 1; s < 64; s <<= 1) {
#pragma unroll
        for (int c = 0; c < 8; ++c) p[c] += __shfl_xor(p[c], s, 64);
    }
    if (lane == 0) {
        float4 o0 = make_float4(p[0] * dd, p[1] * dd, p[2] * dd, p[3] * dd);
        float4 o1 = make_float4(p[4] * dd, p[5] * dd, p[6] * dd, p[7] * dd);
        float4* yo = (float4*)(y2 + (size_t)d * 8);
        yo[0] = o0; yo[1] = o1;
    }
}

// ---------- Aggregation 2 + bias + log_softmax -> out ------------------------
// 8 lanes per node (one per class).
__global__ __launch_bounds__(256) void k_agg2(const float* __restrict__ y2,
                                              const int* __restrict__ srcs,
                                              const int* __restrict__ offs,
                                              const int* __restrict__ count,
                                              const float* __restrict__ dis,
                                              const float* __restrict__ b2,
                                              float* __restrict__ out) {
    int g = (blockIdx.x * 256 + threadIdx.x) >> 3;   // node
    int c = threadIdx.x & 7;                         // class
    if (g >= N_NODES) return;
    float acc = y2[(size_t)g * 8 + c];               // self-loop term
    float acc2 = 0.0f;
    int st = offs[g], n = count[g];
    int i = 0;
    for (; i + 2 <= n; i += 2) {
        int s0 = srcs[st + i], s1 = srcs[st + i + 1];
        acc  += y2[(size_t)s0 * 8 + c];
        acc2 += y2[(size_t)s1 * 8 + c];
    }
    if (i < n) acc += y2[(size_t)srcs[st + i] * 8 + c];
    acc += acc2;

    float o = fmaf(acc, dis[g], b2[c]);
    float m = o;
#pragma unroll
    for (int k = 1; k < 8; k <<= 1) m = fmaxf(m, __shfl_xor(m, k, 64));
    float e = expf(o - m);
    float ssum = e;
#pragma unroll
    for (int k = 1; k < 8; k <<= 1) ssum += __shfl_xor(ssum, k, 64);
    out[(size_t)g * 8 + c] = (o - m) - logf(ssum);
}

// ---------- host launcher -----------------------------------------------------
extern "C" void kernel_launch(void* const* d_in, const int* in_sizes, int n_in,
                              void* d_out, int out_size, void* d_ws, size_t ws_size,
                              hipStream_t stream) {
    const float* x  = (const float*)d_in[0];
    const int*   ei = (const int*)d_in[1];
    const float* W1 = (const float*)d_in[2];
    const float* b1 = (const float*)d_in[3];
    const float* W2 = (const float*)d_in[4];
    const float* b2 = (const float*)d_in[5];
    float* out = (float*)d_out;
    const int E = in_sizes[1] / 2;     // logical edge count

    // workspace layout (all 16B-aligned)
    char* ws = (char*)d_ws;
    int*   flag   = (int*)ws;                       // 4 B (pad to 256)
    int*   count  = (int*)(ws + 256);               // N ints
    int*   offs   = count + N_NODES;                // N ints
    int*   cursor = offs + N_NODES;                 // N ints
    int*   bsum   = cursor + N_NODES;               // 512 ints
    float* dis    = (float*)(bsum + 512);           // N floats
    int*   srcs   = (int*)(dis + N_NODES);          // E ints
    uint*  y1     = (uint*)(srcs + E);              // N*64 uints (bf16 x2)
    float* y2     = (float*)(y1 + (size_t)N_NODES * 64);  // N*8 floats

    const int NB = (N_NODES + 255) / 256;           // 391
    const int EB = (E + 255) / 256;

    k_init  <<<NB, 256, 0, stream>>>(count, flag, ei);
    k_count <<<EB, 256, 0, stream>>>(ei, count, E, flag);
    k_scan1 <<<NB, 256, 0, stream>>>(count, offs, bsum);
    k_scan2 <<<1, 512, 0, stream>>>(bsum, NB);
    k_scan3 <<<NB, 256, 0, stream>>>(offs, bsum, cursor, count, dis);
    k_fill  <<<EB, 256, 0, stream>>>(ei, cursor, srcs, E, flag);

    k_gemm1 <<<N_NODES / 32, 256, 0, stream>>>(x, W1, dis, y1);
    k_agg1  <<<(N_NODES + 3) / 4, 256, 0, stream>>>(y1, srcs, offs, count, dis, b1, W2, y2);
    k_agg2  <<<(N_NODES + 31) / 32, 256, 0, stream>>>(y2, srcs, offs, count, dis, b2, out);
}

// Round 4
// 246.082 us; speedup vs baseline: 1.9668x; 1.6133x over previous
//
#include <hip/hip_runtime.h>

#define N_NODES 100000
#define NBKT 782              // ceil(100000/128) buckets of 128 dst nodes
#define EPB 8192              // edges per partition block

typedef unsigned int uint;

// ---------- bf16 helpers ------------------------------------------------------
__device__ __forceinline__ uint pack_bf16_2(float a, float b) {
    uint ua = __float_as_uint(a), ub = __float_as_uint(b);
    ua += 0x7fff + ((ua >> 16) & 1);           // RNE
    ub += 0x7fff + ((ub >> 16) & 1);
    return (ua >> 16) | (ub & 0xffff0000u);
}
__device__ __forceinline__ float bf_lo(uint u) { return __uint_as_float(u << 16); }
__device__ __forceinline__ float bf_hi(uint u) { return __uint_as_float(u & 0xffff0000u); }

// ---------- edge-index access (handles int32 or raw int64 little-endian) ----
__device__ __forceinline__ int edge_at(const int* __restrict__ ei, int idx, int is64) {
    return is64 ? ei[2 * idx] : ei[idx];
}

// ---------- zero bucket counters + int32/int64 layout probe ------------------
__global__ void k_zero(int* __restrict__ bkt_cnt, int* __restrict__ flag,
                       const int* __restrict__ ei) {
    int i = blockIdx.x * 256 + threadIdx.x;
    if (i < NBKT) bkt_cnt[i] = 0;
    if (blockIdx.x == 0) {
        if (threadIdx.x == 0) flag[0] = 0;
        __syncthreads();
        int any = 0;
        for (int j = threadIdx.x; j < 4096; j += 256) any |= ei[2 * j + 1];
        if (any) atomicOr(flag, 1);            // nonzero odd words -> int32 layout
    }
}

// ---------- phase A1: bucket histogram (LDS-staged) ---------------------------
__global__ __launch_bounds__(256) void kA1(const int* __restrict__ ei, int E,
                                           const int* __restrict__ flag,
                                           int* __restrict__ bkt_cnt) {
    __shared__ int h[NBKT];
    int t = threadIdx.x;
    for (int i = t; i < NBKT; i += 256) h[i] = 0;
    __syncthreads();
    int is64 = (flag[0] == 0);
    int base = blockIdx.x * EPB;
    int end = min(base + EPB, E);
    for (int e = base + t; e < end; e += 256) {
        int d = edge_at(ei, E + e, is64);
        atomicAdd(&h[d >> 7], 1);
    }
    __syncthreads();
    for (int i = t; i < NBKT; i += 256)
        if (h[i]) atomicAdd(&bkt_cnt[i], h[i]);
}

// ---------- phase A2: exclusive scan of 782 bucket counts (1 block) ----------
__global__ __launch_bounds__(1024) void kA2(const int* __restrict__ bkt_cnt,
                                            int* __restrict__ bkt_off,
                                            int* __restrict__ bkt_cursor) {
    __shared__ int s[1024];
    int t = threadIdx.x;
    int v = (t < NBKT) ? bkt_cnt[t] : 0;
    s[t] = v;
    __syncthreads();
    for (int d = 1; d < 1024; d <<= 1) {
        int y = (t >= d) ? s[t - d] : 0;
        __syncthreads();
        s[t] += y;
        __syncthreads();
    }
    if (t < NBKT) {
        int o = s[t] - v;                      // exclusive
        bkt_off[t] = o;
        bkt_cursor[t] = o;
    }
}

// ---------- phase A3: partition edges into bucket-major records --------------
// record = (src << 7) | (dst & 127); per-block LDS binning -> chunked writes.
__global__ __launch_bounds__(256) void kA3(const int* __restrict__ ei, int E,
                                           const int* __restrict__ flag,
                                           int* __restrict__ bkt_cursor,
                                           uint* __restrict__ bkt_data) {
    __shared__ int h[NBKT];
    __shared__ int base[NBKT];
    int t = threadIdx.x;
    for (int i = t; i < NBKT; i += 256) h[i] = 0;
    __syncthreads();
    int is64 = (flag[0] == 0);
    int lo = blockIdx.x * EPB;
    int end = min(lo + EPB, E);
    for (int e = lo + t; e < end; e += 256) {
        int d = edge_at(ei, E + e, is64);
        atomicAdd(&h[d >> 7], 1);
    }
    __syncthreads();
    for (int i = t; i < NBKT; i += 256) {
        int c = h[i];
        base[i] = c ? atomicAdd(&bkt_cursor[i], c) : 0;
    }
    __syncthreads();
    for (int i = t; i < NBKT; i += 256) h[i] = 0;   // reuse as local rank cursor
    __syncthreads();
    for (int e = lo + t; e < end; e += 256) {
        int d = edge_at(ei, E + e, is64);
        int s = edge_at(ei, e, is64);
        int b = d >> 7;
        int r = atomicAdd(&h[b], 1);
        bkt_data[base[b] + r] = ((uint)s << 7) | (uint)(d & 127);
    }
}

// ---------- phase B: per-bucket CSR build + degrees + dis --------------------
// One block per bucket; all srcs writes land in one contiguous ~8KB slice.
__global__ __launch_bounds__(256) void kB(const uint* __restrict__ bkt_data,
                                          const int* __restrict__ bkt_off,
                                          const int* __restrict__ bkt_cnt,
                                          int* __restrict__ srcs,
                                          int* __restrict__ count,
                                          int* __restrict__ offs,
                                          float* __restrict__ dis) {
    __shared__ int lc[128];    // local degree
    __shared__ int sc[128];    // inclusive scan
    __shared__ int lcur[128];  // local fill cursor
    int t = threadIdx.x;
    int b = blockIdx.x;
    if (t < 128) { lc[t] = 0; lcur[t] = 0; }
    __syncthreads();
    int start = bkt_off[b];
    int n = bkt_cnt[b];
    for (int i = t; i < n; i += 256)
        atomicAdd(&lc[bkt_data[start + i] & 127], 1);
    __syncthreads();
    if (t < 128) sc[t] = lc[t];
    __syncthreads();
    for (int d = 1; d < 128; d <<= 1) {
        int y = 0;
        if (t < 128 && t >= d) y = sc[t - d];
        __syncthreads();
        if (t < 128) sc[t] += y;
        __syncthreads();
    }
    if (t < 128) {
        int node = b * 128 + t;
        if (node < N_NODES) {
            int c = lc[t];
            count[node] = c;
            offs[node] = start + sc[t] - c;     // exclusive local offset
            dis[node] = rsqrtf((float)c + 1.0f);
        }
    }
    __syncthreads();
    for (int i = t; i < n; i += 256) {
        uint rec = bkt_data[start + i];
        int dl = rec & 127;
        int r = atomicAdd(&lcur[dl], 1);
        srcs[start + (sc[dl] - lc[dl]) + r] = rec >> 7;
    }
}

// ---------- GEMM1: y1 = bf16((x @ W1) * dis[row])  [100000,128]x[128,128] ----
__global__ __launch_bounds__(256) void k_gemm1(const float* __restrict__ x,
                                               const float* __restrict__ W,
                                               const float* __restrict__ dis,
                                               uint* __restrict__ y1) {
    __shared__ float Wl[64 * 128];   // 32 KB
    __shared__ float Xl[32 * 128];   // 16 KB
    int t = threadIdx.x;
    int row0 = blockIdx.x * 32;

    const float4* X4 = (const float4*)(x + (size_t)row0 * 128);
    float4* Xl4 = (float4*)Xl;
#pragma unroll
    for (int i = 0; i < 4; ++i) Xl4[t + 256 * i] = X4[t + 256 * i];

    int cg = t & 31;   // cols 4cg..4cg+3
    int rg = t >> 5;   // rows 4rg..4rg+3
    float acc[4][4] = {};
    float4* Wl4 = (float4*)Wl;
    const float4* W4 = (const float4*)W;

    for (int kh = 0; kh < 2; ++kh) {
        __syncthreads();
#pragma unroll
        for (int i = 0; i < 8; ++i) Wl4[t + 256 * i] = W4[kh * 2048 + t + 256 * i];
        __syncthreads();
        for (int k = 0; k < 64; ++k) {
            float4 w = Wl4[k * 32 + cg];
#pragma unroll
            for (int r = 0; r < 4; ++r) {
                float xv = Xl[(4 * rg + r) * 128 + kh * 64 + k];
                acc[r][0] = fmaf(xv, w.x, acc[r][0]);
                acc[r][1] = fmaf(xv, w.y, acc[r][1]);
                acc[r][2] = fmaf(xv, w.z, acc[r][2]);
                acc[r][3] = fmaf(xv, w.w, acc[r][3]);
            }
        }
    }
#pragma unroll
    for (int r = 0; r < 4; ++r) {
        int row = row0 + 4 * rg + r;
        float dd = dis[row];
        uint2 o;
        o.x = pack_bf16_2(acc[r][0] * dd, acc[r][1] * dd);
        o.y = pack_bf16_2(acc[r][2] * dd, acc[r][3] * dd);
        ((uint2*)y1)[row * 32 + cg] = o;       // row = 64 uints
    }
}

// ---------- Aggregation 1 fused with GEMM2 -----------------------------------
// One wave per node; h-row (128 vals, 2/lane) never hits memory.
__global__ __launch_bounds__(256) void k_agg1(const uint* __restrict__ y1,
                                              const int* __restrict__ srcs,
                                              const int* __restrict__ offs,
                                              const int* __restrict__ count,
                                              const float* __restrict__ dis,
                                              const float* __restrict__ b1,
                                              const float* __restrict__ W2,
                                              float* __restrict__ y2) {
    __shared__ float W2l[128 * 8];             // 4 KB
    int t = threadIdx.x;
    for (int i = t; i < 1024; i += 256) W2l[i] = W2[i];
    __syncthreads();

    int wave = (blockIdx.x * 256 + t) >> 6;
    int lane = t & 63;
    if (wave >= N_NODES) return;
    int d = wave;

    uint us = y1[(size_t)d * 64 + lane];       // self-loop term
    float ax = bf_lo(us), ay = bf_hi(us);
    float bx = 0.0f, by = 0.0f;

    int st = offs[d], n = count[d];
    int i = 0;
    for (; i + 4 <= n; i += 4) {               // 4 independent gathers in flight
        int s0 = srcs[st + i], s1 = srcs[st + i + 1];
        int s2 = srcs[st + i + 2], s3 = srcs[st + i + 3];
        uint u0 = y1[(size_t)s0 * 64 + lane];
        uint u1 = y1[(size_t)s1 * 64 + lane];
        uint u2 = y1[(size_t)s2 * 64 + lane];
        uint u3 = y1[(size_t)s3 * 64 + lane];
        ax += bf_lo(u0); ay += bf_hi(u0);
        bx += bf_lo(u1); by += bf_hi(u1);
        ax += bf_lo(u2); ay += bf_hi(u2);
        bx += bf_lo(u3); by += bf_hi(u3);
    }
    for (; i < n; ++i) {
        uint u = y1[(size_t)srcs[st + i] * 64 + lane];
        ax += bf_lo(u); ay += bf_hi(u);
    }
    ax += bx; ay += by;

    float dd = dis[d];
    float2 b = ((const float2*)b1)[lane];
    float h0 = fmaxf(fmaf(ax, dd, b.x), 0.0f);
    float h1 = fmaxf(fmaf(ay, dd, b.y), 0.0f);

    // fused GEMM2: p[c] = h0*W2[2*lane][c] + h1*W2[2*lane+1][c], reduce lanes
    const float4* wrow = (const float4*)&W2l[2 * lane * 8];
    float4 wa0 = wrow[0], wa1 = wrow[1];
    float4 wb0 = wrow[2], wb1 = wrow[3];
    float p[8];
    p[0] = h0 * wa0.x + h1 * wb0.x;  p[1] = h0 * wa0.y + h1 * wb0.y;
    p[2] = h0 * wa0.z + h1 * wb0.z;  p[3] = h0 * wa0.w + h1 * wb0.w;
    p[4] = h0 * wa1.x + h1 * wb1.x;  p[5] = h0 * wa1.y + h1 * wb1.y;
    p[6] = h0 * wa1.z + h1 * wb1.z;  p[7] = h0 * wa1.w + h1 * wb1.w;
#pragma unroll
    for (int s = 1; s < 64; s <<= 1) {
#pragma unroll
        for (int c = 0; c < 8; ++c) p[c] += __shfl_xor(p[c], s, 64);
    }
    if (lane == 0) {
        float4 o0 = make_float4(p[0] * dd, p[1] * dd, p[2] * dd, p[3] * dd);
        float4 o1 = make_float4(p[4] * dd, p[5] * dd, p[6] * dd, p[7] * dd);
        float4* yo = (float4*)(y2 + (size_t)d * 8);
        yo[0] = o0; yo[1] = o1;
    }
}

// ---------- Aggregation 2 + bias + log_softmax -> out ------------------------
__global__ __launch_bounds__(256) void k_agg2(const float* __restrict__ y2,
                                              const int* __restrict__ srcs,
                                              const int* __restrict__ offs,
                                              const int* __restrict__ count,
                                              const float* __restrict__ dis,
                                              const float* __restrict__ b2,
                                              float* __restrict__ out) {
    int g = (blockIdx.x * 256 + threadIdx.x) >> 3;   // node
    int c = threadIdx.x & 7;                         // class
    if (g >= N_NODES) return;
    float acc = y2[(size_t)g * 8 + c];               // self-loop term
    float acc2 = 0.0f;
    int st = offs[g], n = count[g];
    int i = 0;
    for (; i + 2 <= n; i += 2) {
        int s0 = srcs[st + i], s1 = srcs[st + i + 1];
        acc  += y2[(size_t)s0 * 8 + c];
        acc2 += y2[(size_t)s1 * 8 + c];
    }
    if (i < n) acc += y2[(size_t)srcs[st + i] * 8 + c];
    acc += acc2;

    float o = fmaf(acc, dis[g], b2[c]);
    float m = o;
#pragma unroll
    for (int k = 1; k < 8; k <<= 1) m = fmaxf(m, __shfl_xor(m, k, 64));
    float e = expf(o - m);
    float ssum = e;
#pragma unroll
    for (int k = 1; k < 8; k <<= 1) ssum += __shfl_xor(ssum, k, 64);
    out[(size_t)g * 8 + c] = (o - m) - logf(ssum);
}

// ---------- host launcher -----------------------------------------------------
extern "C" void kernel_launch(void* const* d_in, const int* in_sizes, int n_in,
                              void* d_out, int out_size, void* d_ws, size_t ws_size,
                              hipStream_t stream) {
    const float* x  = (const float*)d_in[0];
    const int*   ei = (const int*)d_in[1];
    const float* W1 = (const float*)d_in[2];
    const float* b1 = (const float*)d_in[3];
    const float* W2 = (const float*)d_in[4];
    const float* b2 = (const float*)d_in[5];
    float* out = (float*)d_out;
    const int E = in_sizes[1] / 2;     // logical edge count

    // workspace layout (16B-aligned blocks)
    char* ws = (char*)d_ws;
    int*   flag       = (int*)ws;                        // 256 B pad
    int*   bkt_cnt    = (int*)(ws + 256);                // 784 ints
    int*   bkt_off    = bkt_cnt + 784;                   // 784 ints
    int*   bkt_cursor = bkt_off + 784;                   // 784 ints
    int*   count      = bkt_cursor + 784;                // N ints
    int*   offs       = count + N_NODES;                 // N ints
    float* dis        = (float*)(offs + N_NODES);        // N floats
    uint*  bkt_data   = (uint*)(dis + N_NODES);          // E uints
    int*   srcs       = (int*)(bkt_data + E);            // E ints
    uint*  y1         = (uint*)(srcs + E);               // N*64 uints (bf16 x2)
    float* y2         = (float*)(y1 + (size_t)N_NODES * 64);  // N*8 floats

    const int PB = (E + EPB - 1) / EPB;             // partition blocks (196)

    k_zero <<<(NBKT + 255) / 256, 256, 0, stream>>>(bkt_cnt, flag, ei);
    kA1    <<<PB, 256, 0, stream>>>(ei, E, flag, bkt_cnt);
    kA2    <<<1, 1024, 0, stream>>>(bkt_cnt, bkt_off, bkt_cursor);
    kA3    <<<PB, 256, 0, stream>>>(ei, E, flag, bkt_cursor, bkt_data);
    kB     <<<NBKT, 256, 0, stream>>>(bkt_data, bkt_off, bkt_cnt, srcs, count, offs, dis);

    k_gemm1<<<N_NODES / 32, 256, 0, stream>>>(x, W1, dis, y1);
    k_agg1 <<<(N_NODES + 3) / 4, 256, 0, stream>>>(y1, srcs, offs, count, dis, b1, W2, y2);
    k_agg2 <<<(N_NODES + 31) / 32, 256, 0, stream>>>(y2, srcs, offs, count, dis, b2, out);
}

// Round 5
// 227.433 us; speedup vs baseline: 2.1281x; 1.0820x over previous
//
#include <hip/hip_runtime.h>

#define N_NODES 100000
#define NBKT 782              // ceil(100000/128) buckets of 128 dst nodes
#define EPB 8192              // edges per partition block
#define SL_STRIDE 800000      // uints per y1 slice = N_NODES*8

typedef unsigned int uint;

// ---------- bf16 helpers ------------------------------------------------------
__device__ __forceinline__ uint pack_bf16_2(float a, float b) {
    uint ua = __float_as_uint(a), ub = __float_as_uint(b);
    ua += 0x7fff + ((ua >> 16) & 1);           // RNE
    ub += 0x7fff + ((ub >> 16) & 1);
    return (ua >> 16) | (ub & 0xffff0000u);
}
__device__ __forceinline__ float bf_lo(uint u) { return __uint_as_float(u << 16); }
__device__ __forceinline__ float bf_hi(uint u) { return __uint_as_float(u & 0xffff0000u); }

// ---------- edge-index access (handles int32 or raw int64 little-endian) ----
__device__ __forceinline__ int edge_at(const int* __restrict__ ei, int idx, int is64) {
    return is64 ? ei[2 * idx] : ei[idx];
}

// ---------- zero y2 + bucket counters + int32/int64 layout probe -------------
__global__ void k_zero(int* __restrict__ bkt_cnt, int* __restrict__ flag,
                       const int* __restrict__ ei, float* __restrict__ y2) {
    int i = blockIdx.x * 256 + threadIdx.x;
    if (i < NBKT) bkt_cnt[i] = 0;
    if (i < N_NODES * 8) y2[i] = 0.0f;
    if (blockIdx.x == 0) {
        if (threadIdx.x == 0) flag[0] = 0;
        __syncthreads();
        int any = 0;
        for (int j = threadIdx.x; j < 4096; j += 256) any |= ei[2 * j + 1];
        if (any) atomicOr(flag, 1);            // nonzero odd words -> int32 layout
    }
}

// ---------- phase A1: bucket histogram (LDS-staged) ---------------------------
__global__ __launch_bounds__(256) void kA1(const int* __restrict__ ei, int E,
                                           const int* __restrict__ flag,
                                           int* __restrict__ bkt_cnt) {
    __shared__ int h[NBKT];
    int t = threadIdx.x;
    for (int i = t; i < NBKT; i += 256) h[i] = 0;
    __syncthreads();
    int is64 = (flag[0] == 0);
    int base = blockIdx.x * EPB;
    int end = min(base + EPB, E);
    for (int e = base + t; e < end; e += 256) {
        int d = edge_at(ei, E + e, is64);
        atomicAdd(&h[d >> 7], 1);
    }
    __syncthreads();
    for (int i = t; i < NBKT; i += 256)
        if (h[i]) atomicAdd(&bkt_cnt[i], h[i]);
}

// ---------- phase A2: exclusive scan of 782 bucket counts (1 block) ----------
__global__ __launch_bounds__(1024) void kA2(const int* __restrict__ bkt_cnt,
                                            int* __restrict__ bkt_off,
                                            int* __restrict__ bkt_cursor) {
    __shared__ int s[1024];
    int t = threadIdx.x;
    int v = (t < NBKT) ? bkt_cnt[t] : 0;
    s[t] = v;
    __syncthreads();
    for (int d = 1; d < 1024; d <<= 1) {
        int y = (t >= d) ? s[t - d] : 0;
        __syncthreads();
        s[t] += y;
        __syncthreads();
    }
    if (t < NBKT) {
        int o = s[t] - v;                      // exclusive
        bkt_off[t] = o;
        bkt_cursor[t] = o;
    }
}

// ---------- phase A3: partition edges into bucket-major records --------------
// record = (src << 7) | (dst & 127); per-block LDS binning -> chunked writes.
__global__ __launch_bounds__(256) void kA3(const int* __restrict__ ei, int E,
                                           const int* __restrict__ flag,
                                           int* __restrict__ bkt_cursor,
                                           uint* __restrict__ bkt_data) {
    __shared__ int h[NBKT];
    __shared__ int base[NBKT];
    int t = threadIdx.x;
    for (int i = t; i < NBKT; i += 256) h[i] = 0;
    __syncthreads();
    int is64 = (flag[0] == 0);
    int lo = blockIdx.x * EPB;
    int end = min(lo + EPB, E);
    for (int e = lo + t; e < end; e += 256) {
        int d = edge_at(ei, E + e, is64);
        atomicAdd(&h[d >> 7], 1);
    }
    __syncthreads();
    for (int i = t; i < NBKT; i += 256) {
        int c = h[i];
        base[i] = c ? atomicAdd(&bkt_cursor[i], c) : 0;
    }
    __syncthreads();
    for (int i = t; i < NBKT; i += 256) h[i] = 0;   // reuse as local rank cursor
    __syncthreads();
    for (int e = lo + t; e < end; e += 256) {
        int d = edge_at(ei, E + e, is64);
        int s = edge_at(ei, e, is64);
        int b = d >> 7;
        int r = atomicAdd(&h[b], 1);
        bkt_data[base[b] + r] = ((uint)s << 7) | (uint)(d & 127);
    }
}

// ---------- phase B: per-bucket CSR build + degrees + dis --------------------
__global__ __launch_bounds__(256) void kB(const uint* __restrict__ bkt_data,
                                          const int* __restrict__ bkt_off,
                                          const int* __restrict__ bkt_cnt,
                                          int* __restrict__ srcs,
                                          int* __restrict__ count,
                                          int* __restrict__ offs,
                                          float* __restrict__ dis) {
    __shared__ int lc[128];    // local degree
    __shared__ int sc[128];    // inclusive scan
    __shared__ int lcur[128];  // local fill cursor
    int t = threadIdx.x;
    int b = blockIdx.x;
    if (t < 128) { lc[t] = 0; lcur[t] = 0; }
    __syncthreads();
    int start = bkt_off[b];
    int n = bkt_cnt[b];
    for (int i = t; i < n; i += 256)
        atomicAdd(&lc[bkt_data[start + i] & 127], 1);
    __syncthreads();
    if (t < 128) sc[t] = lc[t];
    __syncthreads();
    for (int d = 1; d < 128; d <<= 1) {
        int y = 0;
        if (t < 128 && t >= d) y = sc[t - d];
        __syncthreads();
        if (t < 128) sc[t] += y;
        __syncthreads();
    }
    if (t < 128) {
        int node = b * 128 + t;
        if (node < N_NODES) {
            int c = lc[t];
            count[node] = c;
            offs[node] = start + sc[t] - c;
            dis[node] = rsqrtf((float)c + 1.0f);
        }
    }
    __syncthreads();
    for (int i = t; i < n; i += 256) {
        uint rec = bkt_data[start + i];
        int dl = rec & 127;
        int r = atomicAdd(&lcur[dl], 1);
        srcs[start + (sc[dl] - lc[dl]) + r] = rec >> 7;
    }
}

// ---------- GEMM1: y1s = bf16((x @ W1) * dis[row]) in SLICED layout ----------
// slice s (8 uints = 16 cols) of row r lives at y1s[s*SL_STRIDE + r*8 .. +7]
__global__ __launch_bounds__(256) void k_gemm1(const float* __restrict__ x,
                                               const float* __restrict__ W,
                                               const float* __restrict__ dis,
                                               uint* __restrict__ y1s) {
    __shared__ float Wl[64 * 128];   // 32 KB
    __shared__ float Xl[32 * 128];   // 16 KB
    int t = threadIdx.x;
    int row0 = blockIdx.x * 32;

    const float4* X4 = (const float4*)(x + (size_t)row0 * 128);
    float4* Xl4 = (float4*)Xl;
#pragma unroll
    for (int i = 0; i < 4; ++i) Xl4[t + 256 * i] = X4[t + 256 * i];

    int cg = t & 31;   // cols 4cg..4cg+3  (uints 2cg,2cg+1; slice cg>>2)
    int rg = t >> 5;   // rows 4rg..4rg+3
    float acc[4][4] = {};
    float4* Wl4 = (float4*)Wl;
    const float4* W4 = (const float4*)W;

    for (int kh = 0; kh < 2; ++kh) {
        __syncthreads();
#pragma unroll
        for (int i = 0; i < 8; ++i) Wl4[t + 256 * i] = W4[kh * 2048 + t + 256 * i];
        __syncthreads();
        for (int k = 0; k < 64; ++k) {
            float4 w = Wl4[k * 32 + cg];
#pragma unroll
            for (int r = 0; r < 4; ++r) {
                float xv = Xl[(4 * rg + r) * 128 + kh * 64 + k];
                acc[r][0] = fmaf(xv, w.x, acc[r][0]);
                acc[r][1] = fmaf(xv, w.y, acc[r][1]);
                acc[r][2] = fmaf(xv, w.z, acc[r][2]);
                acc[r][3] = fmaf(xv, w.w, acc[r][3]);
            }
        }
    }
    int slice = cg >> 2, sp = cg & 3;              // position within slice (uint2)
#pragma unroll
    for (int r = 0; r < 4; ++r) {
        int row = row0 + 4 * rg + r;
        float dd = dis[row];
        uint2 o;
        o.x = pack_bf16_2(acc[r][0] * dd, acc[r][1] * dd);
        o.y = pack_bf16_2(acc[r][2] * dd, acc[r][3] * dd);
        ((uint2*)y1s)[(size_t)slice * (SL_STRIDE / 2) + row * 4 + sp] = o;
    }
}

// ---------- Aggregation 1 (sliced, XCD-local) fused with partial GEMM2 -------
// slice = blockIdx.x % 8 (round-robin XCD binding). 8-lane group per node.
// Each group aggregates 16 cols, computes h-slice, partial y2 -> atomicAdd.
__global__ __launch_bounds__(256) void k_agg1s(const uint* __restrict__ y1s,
                                               const int* __restrict__ srcs,
                                               const int* __restrict__ offs,
                                               const int* __restrict__ count,
                                               const float* __restrict__ dis,
                                               const float* __restrict__ b1,
                                               const float* __restrict__ W2,
                                               float* __restrict__ y2) {
    int t = threadIdx.x;
    int slice = blockIdx.x & 7;
    int nb = blockIdx.x >> 3;
    int g = t >> 3;                    // group 0..31
    int j = t & 7;                     // lane in group
    int d = nb * 32 + g;               // node (3125*32 == 100000, no tail)

    // W2 rows for this lane (fixed): rows slice*16+2j, +2j+1
    float w0[8], w1[8];
    const float* wr0 = W2 + (size_t)(slice * 16 + 2 * j) * 8;
#pragma unroll
    for (int c = 0; c < 8; ++c) { w0[c] = wr0[c]; w1[c] = wr0[8 + c]; }

    const uint* ybase = y1s + (size_t)slice * SL_STRIDE;
    uint us = ybase[(size_t)d * 8 + j];          // self-loop term
    float ax = bf_lo(us), ay = bf_hi(us);

    int st = offs[d], n = count[d];
    int i = 0;
    for (; i + 8 <= n; i += 8) {
        int s = srcs[st + i + j];                // 8 consecutive edges, coalesced
#pragma unroll
        for (int k = 0; k < 8; ++k) {
            int sk = __shfl(s, k, 8);
            uint u = ybase[(size_t)sk * 8 + j];
            ax += bf_lo(u); ay += bf_hi(u);
        }
    }
    int rem = n - i;
    if (rem > 0) {
        int s = (j < rem) ? srcs[st + i + j] : 0;
        for (int k = 0; k < rem; ++k) {
            int sk = __shfl(s, k, 8);
            uint u = ybase[(size_t)sk * 8 + j];
            ax += bf_lo(u); ay += bf_hi(u);
        }
    }

    float dd = dis[d];
    float2 b = ((const float2*)b1)[slice * 8 + j];
    float h0 = fmaxf(fmaf(ax, dd, b.x), 0.0f);
    float h1 = fmaxf(fmaf(ay, dd, b.y), 0.0f);

    float p[8];
#pragma unroll
    for (int c = 0; c < 8; ++c) p[c] = h0 * w0[c] + h1 * w1[c];
#pragma unroll
    for (int sft = 1; sft < 8; sft <<= 1) {
#pragma unroll
        for (int c = 0; c < 8; ++c) p[c] += __shfl_xor(p[c], sft, 8);
    }
    atomicAdd(&y2[(size_t)d * 8 + j], p[j] * dd);   // lane j owns class j
}

// ---------- Aggregation 2 + bias + log_softmax -> out ------------------------
__global__ __launch_bounds__(256) void k_agg2(const float* __restrict__ y2,
                                              const int* __restrict__ srcs,
                                              const int* __restrict__ offs,
                                              const int* __restrict__ count,
                                              const float* __restrict__ dis,
                                              const float* __restrict__ b2,
                                              float* __restrict__ out) {
    int g = (blockIdx.x * 256 + threadIdx.x) >> 3;   // node
    int c = threadIdx.x & 7;                         // class
    if (g >= N_NODES) return;
    float acc = y2[(size_t)g * 8 + c];               // self-loop term
    float acc2 = 0.0f;
    int st = offs[g], n = count[g];
    int i = 0;
    for (; i + 2 <= n; i += 2) {
        int s0 = srcs[st + i], s1 = srcs[st + i + 1];
        acc  += y2[(size_t)s0 * 8 + c];
        acc2 += y2[(size_t)s1 * 8 + c];
    }
    if (i < n) acc += y2[(size_t)srcs[st + i] * 8 + c];
    acc += acc2;

    float o = fmaf(acc, dis[g], b2[c]);
    float m = o;
#pragma unroll
    for (int k = 1; k < 8; k <<= 1) m = fmaxf(m, __shfl_xor(m, k, 64));
    float e = expf(o - m);
    float ssum = e;
#pragma unroll
    for (int k = 1; k < 8; k <<= 1) ssum += __shfl_xor(ssum, k, 64);
    out[(size_t)g * 8 + c] = (o - m) - logf(ssum);
}

// ---------- host launcher -----------------------------------------------------
extern "C" void kernel_launch(void* const* d_in, const int* in_sizes, int n_in,
                              void* d_out, int out_size, void* d_ws, size_t ws_size,
                              hipStream_t stream) {
    const float* x  = (const float*)d_in[0];
    const int*   ei = (const int*)d_in[1];
    const float* W1 = (const float*)d_in[2];
    const float* b1 = (const float*)d_in[3];
    const float* W2 = (const float*)d_in[4];
    const float* b2 = (const float*)d_in[5];
    float* out = (float*)d_out;
    const int E = in_sizes[1] / 2;     // logical edge count

    // workspace layout (16B-aligned blocks)
    char* ws = (char*)d_ws;
    int*   flag       = (int*)ws;                        // 256 B pad
    int*   bkt_cnt    = (int*)(ws + 256);                // 784 ints
    int*   bkt_off    = bkt_cnt + 784;                   // 784 ints
    int*   bkt_cursor = bkt_off + 784;                   // 784 ints
    int*   count      = bkt_cursor + 784;                // N ints
    int*   offs       = count + N_NODES;                 // N ints
    float* dis        = (float*)(offs + N_NODES);        // N floats
    uint*  bkt_data   = (uint*)(dis + N_NODES);          // E uints
    int*   srcs       = (int*)(bkt_data + E);            // E ints
    uint*  y1s        = (uint*)(srcs + E);               // 8 slices * N*8 uints
    float* y2         = (float*)(y1s + (size_t)8 * SL_STRIDE);  // N*8 floats

    const int PB = (E + EPB - 1) / EPB;             // partition blocks

    k_zero <<<3125, 256, 0, stream>>>(bkt_cnt, flag, ei, y2);
    kA1    <<<PB, 256, 0, stream>>>(ei, E, flag, bkt_cnt);
    kA2    <<<1, 1024, 0, stream>>>(bkt_cnt, bkt_off, bkt_cursor);
    kA3    <<<PB, 256, 0, stream>>>(ei, E, flag, bkt_cursor, bkt_data);
    kB     <<<NBKT, 256, 0, stream>>>(bkt_data, bkt_off, bkt_cnt, srcs, count, offs, dis);

    k_gemm1<<<N_NODES / 32, 256, 0, stream>>>(x, W1, dis, y1s);
    k_agg1s<<<8 * 3125, 256, 0, stream>>>(y1s, srcs, offs, count, dis, b1, W2, y2);
    k_agg2 <<<(N_NODES + 31) / 32, 256, 0, stream>>>(y2, srcs, offs, count, dis, b2, out);
}

// Round 6
// 226.060 us; speedup vs baseline: 2.1410x; 1.0061x over previous
//
#include <hip/hip_runtime.h>

#define N_NODES 100000
#define NBKT 782              // ceil(100000/128) buckets of 128 dst nodes
#define EPB 8192              // edges per partition block
#define SL_STRIDE 800000      // uints per y1 slice = N_NODES*8

typedef unsigned int uint;

// ---------- bf16 helpers ------------------------------------------------------
__device__ __forceinline__ uint pack_bf16_2(float a, float b) {
    uint ua = __float_as_uint(a), ub = __float_as_uint(b);
    ua += 0x7fff + ((ua >> 16) & 1);           // RNE
    ub += 0x7fff + ((ub >> 16) & 1);
    return (ua >> 16) | (ub & 0xffff0000u);
}
__device__ __forceinline__ float bf_lo(uint u) { return __uint_as_float(u << 16); }
__device__ __forceinline__ float bf_hi(uint u) { return __uint_as_float(u & 0xffff0000u); }

// ---------- edge-index access (handles int32 or raw int64 little-endian) ----
__device__ __forceinline__ int edge_at(const int* __restrict__ ei, int idx, int is64) {
    return is64 ? ei[2 * idx] : ei[idx];
}

// ---------- zero y2 + bucket counters + int32/int64 layout probe -------------
__global__ void k_zero(int* __restrict__ bkt_cnt, int* __restrict__ flag,
                       const int* __restrict__ ei, float* __restrict__ y2) {
    int i = blockIdx.x * 256 + threadIdx.x;
    if (i < NBKT) bkt_cnt[i] = 0;
    if (i < N_NODES * 8) y2[i] = 0.0f;
    if (blockIdx.x == 0) {
        if (threadIdx.x == 0) flag[0] = 0;
        __syncthreads();
        int any = 0;
        for (int j = threadIdx.x; j < 4096; j += 256) any |= ei[2 * j + 1];
        if (any) atomicOr(flag, 1);            // nonzero odd words -> int32 layout
    }
}

// ---------- phase A1: bucket histogram (LDS-staged) ---------------------------
__global__ __launch_bounds__(256) void kA1(const int* __restrict__ ei, int E,
                                           const int* __restrict__ flag,
                                           int* __restrict__ bkt_cnt) {
    __shared__ int h[NBKT];
    int t = threadIdx.x;
    for (int i = t; i < NBKT; i += 256) h[i] = 0;
    __syncthreads();
    int is64 = (flag[0] == 0);
    int base = blockIdx.x * EPB;
    int end = min(base + EPB, E);
    for (int e = base + t; e < end; e += 256) {
        int d = edge_at(ei, E + e, is64);
        atomicAdd(&h[d >> 7], 1);
    }
    __syncthreads();
    for (int i = t; i < NBKT; i += 256)
        if (h[i]) atomicAdd(&bkt_cnt[i], h[i]);
}

// ---------- phase A2: exclusive scan of 782 bucket counts (1 block) ----------
__global__ __launch_bounds__(1024) void kA2(const int* __restrict__ bkt_cnt,
                                            int* __restrict__ bkt_off,
                                            int* __restrict__ bkt_cursor) {
    __shared__ int s[1024];
    int t = threadIdx.x;
    int v = (t < NBKT) ? bkt_cnt[t] : 0;
    s[t] = v;
    __syncthreads();
    for (int d = 1; d < 1024; d <<= 1) {
        int y = (t >= d) ? s[t - d] : 0;
        __syncthreads();
        s[t] += y;
        __syncthreads();
    }
    if (t < NBKT) {
        int o = s[t] - v;                      // exclusive
        bkt_off[t] = o;
        bkt_cursor[t] = o;
    }
}

// ---------- phase A3: partition edges into bucket-major records --------------
// record = (src << 7) | (dst & 127); per-block LDS binning -> chunked writes.
__global__ __launch_bounds__(256) void kA3(const int* __restrict__ ei, int E,
                                           const int* __restrict__ flag,
                                           int* __restrict__ bkt_cursor,
                                           uint* __restrict__ bkt_data) {
    __shared__ int h[NBKT];
    __shared__ int base[NBKT];
    int t = threadIdx.x;
    for (int i = t; i < NBKT; i += 256) h[i] = 0;
    __syncthreads();
    int is64 = (flag[0] == 0);
    int lo = blockIdx.x * EPB;
    int end = min(lo + EPB, E);
    for (int e = lo + t; e < end; e += 256) {
        int d = edge_at(ei, E + e, is64);
        atomicAdd(&h[d >> 7], 1);
    }
    __syncthreads();
    for (int i = t; i < NBKT; i += 256) {
        int c = h[i];
        base[i] = c ? atomicAdd(&bkt_cursor[i], c) : 0;
    }
    __syncthreads();
    for (int i = t; i < NBKT; i += 256) h[i] = 0;   // reuse as local rank cursor
    __syncthreads();
    for (int e = lo + t; e < end; e += 256) {
        int d = edge_at(ei, E + e, is64);
        int s = edge_at(ei, e, is64);
        int b = d >> 7;
        int r = atomicAdd(&h[b], 1);
        bkt_data[base[b] + r] = ((uint)s << 7) | (uint)(d & 127);
    }
}

// ---------- phase B: per-bucket CSR build + degrees + dis --------------------
__global__ __launch_bounds__(256) void kB(const uint* __restrict__ bkt_data,
                                          const int* __restrict__ bkt_off,
                                          const int* __restrict__ bkt_cnt,
                                          int* __restrict__ srcs,
                                          int* __restrict__ count,
                                          int* __restrict__ offs,
                                          float* __restrict__ dis) {
    __shared__ int lc[128];    // local degree
    __shared__ int sc[128];    // inclusive scan
    __shared__ int lcur[128];  // local fill cursor
    int t = threadIdx.x;
    int b = blockIdx.x;
    if (t < 128) { lc[t] = 0; lcur[t] = 0; }
    __syncthreads();
    int start = bkt_off[b];
    int n = bkt_cnt[b];
    for (int i = t; i < n; i += 256)
        atomicAdd(&lc[bkt_data[start + i] & 127], 1);
    __syncthreads();
    if (t < 128) sc[t] = lc[t];
    __syncthreads();
    for (int d = 1; d < 128; d <<= 1) {
        int y = 0;
        if (t < 128 && t >= d) y = sc[t - d];
        __syncthreads();
        if (t < 128) sc[t] += y;
        __syncthreads();
    }
    if (t < 128) {
        int node = b * 128 + t;
        if (node < N_NODES) {
            int c = lc[t];
            count[node] = c;
            offs[node] = start + sc[t] - c;
            dis[node] = rsqrtf((float)c + 1.0f);
        }
    }
    __syncthreads();
    for (int i = t; i < n; i += 256) {
        uint rec = bkt_data[start + i];
        int dl = rec & 127;
        int r = atomicAdd(&lcur[dl], 1);
        srcs[start + (sc[dl] - lc[dl]) + r] = rec >> 7;
    }
}

// ---------- GEMM1: y1s = bf16((x @ W1) * dis[row]) in SLICED layout ----------
// slice s (8 uints = 16 cols) of row r lives at y1s[s*SL_STRIDE + r*8 .. +7]
__global__ __launch_bounds__(256) void k_gemm1(const float* __restrict__ x,
                                               const float* __restrict__ W,
                                               const float* __restrict__ dis,
                                               uint* __restrict__ y1s) {
    __shared__ float Wl[64 * 128];   // 32 KB
    __shared__ float Xl[32 * 128];   // 16 KB
    int t = threadIdx.x;
    int row0 = blockIdx.x * 32;

    const float4* X4 = (const float4*)(x + (size_t)row0 * 128);
    float4* Xl4 = (float4*)Xl;
#pragma unroll
    for (int i = 0; i < 4; ++i) Xl4[t + 256 * i] = X4[t + 256 * i];

    int cg = t & 31;   // cols 4cg..4cg+3  (uints 2cg,2cg+1; slice cg>>2)
    int rg = t >> 5;   // rows 4rg..4rg+3
    float acc[4][4] = {};
    float4* Wl4 = (float4*)Wl;
    const float4* W4 = (const float4*)W;

    for (int kh = 0; kh < 2; ++kh) {
        __syncthreads();
#pragma unroll
        for (int i = 0; i < 8; ++i) Wl4[t + 256 * i] = W4[kh * 2048 + t + 256 * i];
        __syncthreads();
        for (int k = 0; k < 64; ++k) {
            float4 w = Wl4[k * 32 + cg];
#pragma unroll
            for (int r = 0; r < 4; ++r) {
                float xv = Xl[(4 * rg + r) * 128 + kh * 64 + k];
                acc[r][0] = fmaf(xv, w.x, acc[r][0]);
                acc[r][1] = fmaf(xv, w.y, acc[r][1]);
                acc[r][2] = fmaf(xv, w.z, acc[r][2]);
                acc[r][3] = fmaf(xv, w.w, acc[r][3]);
            }
        }
    }
    int slice = cg >> 2, sp = cg & 3;              // position within slice (uint2)
#pragma unroll
    for (int r = 0; r < 4; ++r) {
        int row = row0 + 4 * rg + r;
        float dd = dis[row];
        uint2 o;
        o.x = pack_bf16_2(acc[r][0] * dd, acc[r][1] * dd);
        o.y = pack_bf16_2(acc[r][2] * dd, acc[r][3] * dd);
        ((uint2*)y1s)[(size_t)slice * (SL_STRIDE / 2) + row * 4 + sp] = o;
    }
}

// ---------- Aggregation 1 (sliced, XCD-local) fused with partial GEMM2 -------
// slice = blockIdx.x % 8 (round-robin XCD binding). 8-lane group per node.
// EDGE-PER-LANE: lane j handles edges i = j, j+8, ...; loads full 32B slice-row
// via 2x dwordx4; accumulates all 16 slice-cols. Self-loop = virtual edge i==n.
// Epilogue: 3-round reduce-scatter -> lane j owns cols 2j,2j+1 -> h -> partial
// W2 product -> class reduce-scatter -> lane j atomicAdds class j.
__global__ __launch_bounds__(256) void k_agg1s(const uint* __restrict__ y1s,
                                               const int* __restrict__ srcs,
                                               const int* __restrict__ offs,
                                               const int* __restrict__ count,
                                               const float* __restrict__ dis,
                                               const float* __restrict__ b1,
                                               const float* __restrict__ W2,
                                               float* __restrict__ y2) {
    int t = threadIdx.x;
    int slice = blockIdx.x & 7;
    int nb = blockIdx.x >> 3;
    int g = t >> 3;                    // group 0..31
    int j = t & 7;                     // lane in group
    int d = nb * 32 + g;               // node (3125*32 == 100000, no tail)

    // W2 rows for this lane (fixed): rows slice*16+2j, slice*16+2j+1
    float w0[8], w1[8];
    const float* wr0 = W2 + (size_t)(slice * 16 + 2 * j) * 8;
#pragma unroll
    for (int c = 0; c < 8; ++c) { w0[c] = wr0[c]; w1[c] = wr0[8 + c]; }

    const uint4* ybase = (const uint4*)(y1s + (size_t)slice * SL_STRIDE);
    float acc[16];
#pragma unroll
    for (int c = 0; c < 16; ++c) acc[c] = 0.0f;

    int st = offs[d], n = count[d];
    for (int i = j; i <= n; i += 8) {            // i==n -> self-loop (one lane)
        int sk = d;
        if (i < n) sk = srcs[st + i];
        uint4 a  = ybase[(size_t)sk * 2];
        uint4 bq = ybase[(size_t)sk * 2 + 1];
        acc[0]  += bf_lo(a.x);  acc[1]  += bf_hi(a.x);
        acc[2]  += bf_lo(a.y);  acc[3]  += bf_hi(a.y);
        acc[4]  += bf_lo(a.z);  acc[5]  += bf_hi(a.z);
        acc[6]  += bf_lo(a.w);  acc[7]  += bf_hi(a.w);
        acc[8]  += bf_lo(bq.x); acc[9]  += bf_hi(bq.x);
        acc[10] += bf_lo(bq.y); acc[11] += bf_hi(bq.y);
        acc[12] += bf_lo(bq.z); acc[13] += bf_hi(bq.z);
        acc[14] += bf_lo(bq.w); acc[15] += bf_hi(bq.w);
    }

    // reduce-scatter: lane j ends with cols 2j (v2[0]) and 2j+1 (v2[1])
    int hi4 = (j >> 2) & 1, hi2 = (j >> 1) & 1, hi1 = j & 1;
    float v8[8];
#pragma unroll
    for (int c = 0; c < 8; ++c) {
        float keep = hi4 ? acc[c + 8] : acc[c];
        float send = hi4 ? acc[c] : acc[c + 8];
        v8[c] = keep + __shfl_xor(send, 4, 8);
    }
    float v4[4];
#pragma unroll
    for (int c = 0; c < 4; ++c) {
        float keep = hi2 ? v8[c + 4] : v8[c];
        float send = hi2 ? v8[c] : v8[c + 4];
        v4[c] = keep + __shfl_xor(send, 2, 8);
    }
    float v2[2];
#pragma unroll
    for (int c = 0; c < 2; ++c) {
        float keep = hi1 ? v4[c + 2] : v4[c];
        float send = hi1 ? v4[c] : v4[c + 2];
        v2[c] = keep + __shfl_xor(send, 1, 8);
    }

    float dd = dis[d];
    float2 b = ((const float2*)b1)[slice * 8 + j];
    float h0 = fmaxf(fmaf(v2[0], dd, b.x), 0.0f);
    float h1 = fmaxf(fmaf(v2[1], dd, b.y), 0.0f);

    // partial GEMM2 for this slice's 2 cols, then class reduce-scatter:
    // lane j ends owning class j (keep-high on bits 2,1,0 of j).
    float p[8];
#pragma unroll
    for (int c = 0; c < 8; ++c) p[c] = h0 * w0[c] + h1 * w1[c];
    float q4[4];
#pragma unroll
    for (int c = 0; c < 4; ++c) {
        float keep = hi4 ? p[c + 4] : p[c];
        float send = hi4 ? p[c] : p[c + 4];
        q4[c] = keep + __shfl_xor(send, 4, 8);
    }
    float q2[2];
#pragma unroll
    for (int c = 0; c < 2; ++c) {
        float keep = hi2 ? q4[c + 2] : q4[c];
        float send = hi2 ? q4[c] : q4[c + 2];
        q2[c] = keep + __shfl_xor(send, 2, 8);
    }
    float keep = hi1 ? q2[1] : q2[0];
    float send = hi1 ? q2[0] : q2[1];
    float q = keep + __shfl_xor(send, 1, 8);   // class 4*hi4+2*hi2+hi1 == j

    atomicAdd(&y2[(size_t)d * 8 + j], q * dd);
}

// ---------- Aggregation 2 + bias + log_softmax -> out ------------------------
__global__ __launch_bounds__(256) void k_agg2(const float* __restrict__ y2,
                                              const int* __restrict__ srcs,
                                              const int* __restrict__ offs,
                                              const int* __restrict__ count,
                                              const float* __restrict__ dis,
                                              const float* __restrict__ b2,
                                              float* __restrict__ out) {
    int g = (blockIdx.x * 256 + threadIdx.x) >> 3;   // node
    int c = threadIdx.x & 7;                         // class
    if (g >= N_NODES) return;
    float acc = y2[(size_t)g * 8 + c];               // self-loop term
    float acc2 = 0.0f;
    int st = offs[g], n = count[g];
    int i = 0;
    for (; i + 2 <= n; i += 2) {
        int s0 = srcs[st + i], s1 = srcs[st + i + 1];
        acc  += y2[(size_t)s0 * 8 + c];
        acc2 += y2[(size_t)s1 * 8 + c];
    }
    if (i < n) acc += y2[(size_t)srcs[st + i] * 8 + c];
    acc += acc2;

    float o = fmaf(acc, dis[g], b2[c]);
    float m = o;
#pragma unroll
    for (int k = 1; k < 8; k <<= 1) m = fmaxf(m, __shfl_xor(m, k, 64));
    float e = expf(o - m);
    float ssum = e;
#pragma unroll
    for (int k = 1; k < 8; k <<= 1) ssum += __shfl_xor(ssum, k, 64);
    out[(size_t)g * 8 + c] = (o - m) - logf(ssum);
}

// ---------- host launcher -----------------------------------------------------
extern "C" void kernel_launch(void* const* d_in, const int* in_sizes, int n_in,
                              void* d_out, int out_size, void* d_ws, size_t ws_size,
                              hipStream_t stream) {
    const float* x  = (const float*)d_in[0];
    const int*   ei = (const int*)d_in[1];
    const float* W1 = (const float*)d_in[2];
    const float* b1 = (const float*)d_in[3];
    const float* W2 = (const float*)d_in[4];
    const float* b2 = (const float*)d_in[5];
    float* out = (float*)d_out;
    const int E = in_sizes[1] / 2;     // logical edge count

    // workspace layout (16B-aligned blocks)
    char* ws = (char*)d_ws;
    int*   flag       = (int*)ws;                        // 256 B pad
    int*   bkt_cnt    = (int*)(ws + 256);                // 784 ints
    int*   bkt_off    = bkt_cnt + 784;                   // 784 ints
    int*   bkt_cursor = bkt_off + 784;                   // 784 ints
    int*   count      = bkt_cursor + 784;                // N ints
    int*   offs       = count + N_NODES;                 // N ints
    float* dis        = (float*)(offs + N_NODES);        // N floats
    uint*  bkt_data   = (uint*)(dis + N_NODES);          // E uints
    int*   srcs       = (int*)(bkt_data + E);            // E ints
    uint*  y1s        = (uint*)(srcs + E);               // 8 slices * N*8 uints
    float* y2         = (float*)(y1s + (size_t)8 * SL_STRIDE);  // N*8 floats

    const int PB = (E + EPB - 1) / EPB;             // partition blocks

    k_zero <<<3125, 256, 0, stream>>>(bkt_cnt, flag, ei, y2);
    kA1    <<<PB, 256, 0, stream>>>(ei, E, flag, bkt_cnt);
    kA2    <<<1, 1024, 0, stream>>>(bkt_cnt, bkt_off, bkt_cursor);
    kA3    <<<PB, 256, 0, stream>>>(ei, E, flag, bkt_cursor, bkt_data);
    kB     <<<NBKT, 256, 0, stream>>>(bkt_data, bkt_off, bkt_cnt, srcs, count, offs, dis);

    k_gemm1<<<N_NODES / 32, 256, 0, stream>>>(x, W1, dis, y1s);
    k_agg1s<<<8 * 3125, 256, 0, stream>>>(y1s, srcs, offs, count, dis, b1, W2, y2);
    k_agg2 <<<(N_NODES + 31) / 32, 256, 0, stream>>>(y2, srcs, offs, count, dis, b2, out);
}